// Round 3
// baseline (676.866 us; speedup 1.0000x reference)
//
#include <hip/hip_runtime.h>
#include <hip/hip_bf16.h>

typedef __attribute__((ext_vector_type(4))) float f32x4;
typedef __attribute__((ext_vector_type(8))) __bf16 bfv8;
typedef __attribute__((ext_vector_type(8))) short sv8;
typedef __attribute__((ext_vector_type(4))) unsigned short usv4;

// ---------------- helpers ----------------

static __device__ __forceinline__ f32x4 mfma16(sv8 a, sv8 b, f32x4 c) {
    return __builtin_amdgcn_mfma_f32_16x16x32_bf16(
        __builtin_bit_cast(bfv8, a), __builtin_bit_cast(bfv8, b), c, 0, 0, 0);
}

static __device__ __forceinline__ unsigned short f2bf(float f) {
    union { float f; unsigned int u; } v; v.f = f;
    unsigned int u = v.u;
    return (unsigned short)((u + 0x7FFFu + ((u >> 16) & 1u)) >> 16);  // RNE
}

// async global->LDS, 16B per lane (dest linear in lane order)
static __device__ __forceinline__ void gld16(void* lds, const void* g) {
    __builtin_amdgcn_global_load_lds(
        (const __attribute__((address_space(1))) unsigned int*)g,
        (__attribute__((address_space(3))) unsigned int*)lds, 16, 0, 0);
}

#define BAR() __builtin_amdgcn_s_barrier()
#define SCHED() __builtin_amdgcn_sched_barrier(0)
#define LGKM0() asm volatile("s_waitcnt lgkmcnt(0)" ::: "memory")

// ---------------- fp32 -> bf16 convert (weights) ----------------

__global__ void cvt_bf16_kernel(const float* __restrict__ in,
                                unsigned short* __restrict__ out, int n4) {
    int i = blockIdx.x * 256 + threadIdx.x;
    if (i >= n4) return;
    float4 f = reinterpret_cast<const float4*>(in)[i];
    usv4 o = { f2bf(f.x), f2bf(f.y), f2bf(f.z), f2bf(f.w) };
    reinterpret_cast<usv4*>(out)[i] = o;
}

// ---------------- LayerNorm fp32 -> bf16, C=768 ----------------

__global__ void ln_kernel(const float* __restrict__ x, const float* __restrict__ w,
                          const float* __restrict__ b, unsigned short* __restrict__ out) {
    const int row = blockIdx.x;
    const int t = threadIdx.x;
    const float* xr = x + (size_t)row * 768;
    float v[3];
    float s = 0.f, ss = 0.f;
#pragma unroll
    for (int i = 0; i < 3; ++i) {
        v[i] = xr[t + i * 256];
        s += v[i]; ss += v[i] * v[i];
    }
#pragma unroll
    for (int o = 32; o; o >>= 1) { s += __shfl_xor(s, o); ss += __shfl_xor(ss, o); }
    __shared__ float red[8];
    if ((t & 63) == 0) { red[t >> 6] = s; red[4 + (t >> 6)] = ss; }
    __syncthreads();
    float S = red[0] + red[1] + red[2] + red[3];
    float SS = red[4] + red[5] + red[6] + red[7];
    float mu = S * (1.0f / 768.0f);
    float var = SS * (1.0f / 768.0f) - mu * mu;
    float rstd = rsqrtf(var + 1e-6f);
#pragma unroll
    for (int i = 0; i < 3; ++i) {
        int c = t + i * 256;
        out[(size_t)row * 768 + c] = f2bf((v[i] - mu) * rstd * w[c] + b[c]);
    }
}

// ---------------- prompt [B,20,2,H,64] fp32 -> K [B,H,224,64], Vt [B,H,64,224] bf16 ----------------

__global__ void prompt_kernel(const float* __restrict__ pr,
                              unsigned short* __restrict__ k_out,
                              unsigned short* __restrict__ v_out) {
    int i = blockIdx.x * 256 + threadIdx.x;  // over B*P*H*64 = 983040
    if (i >= 64 * 20 * 12 * 64) return;
    int d = i & 63;
    int t = i >> 6;
    int h = t % 12;
    int t2 = t / 12;
    int p = t2 % 20;
    int b = t2 / 20;
    size_t src = ((((size_t)b * 20 + p) * 2 + 0) * 12 + h) * 64 + d;
    float kv = pr[src];
    float vv = pr[src + 12 * 64];  // s=1 plane
    k_out[(((size_t)(b * 12 + h) * 224 + p) << 6) + d] = f2bf(kv);
    v_out[((size_t)(b * 12 + h) * 64 + d) * 224 + p] = f2bf(vv);
}

// ---------------- 256x256 8-phase bf16 GEMM: C[M,N] = A[M,K] @ W[N,K]^T ----------------
// BK=64, 512 threads = 8 waves (2M x 4N), per-wave 128x64 output (8x4 16x16 frags).
// LDS 128 KiB: [2 dbuf][A,B][256 rows][64 k-elems], XOR swizzle slot^=(row&7),
// applied linear-dest + inverse-swizzled-source (gld_lds) + swizzled ds_read.
// Per K-tile: 4 phases; counted vmcnt(4) once per K-tile (T4); setprio around MFMA (T5).
// Staging ledger (K-tile t): ph1->B_lo(t+1), ph2->B_hi(t+1), ph3->A_lo(t+2), ph4->A_hi(t+2).
// Reads: A halves done by end ph2, B halves by end ph3 -> stage slots are race-free
// (every stage-issue is after a barrier that follows the region's last lgkmcnt(0)).

#define EPI_QKV 0
#define EPI_RES 1
#define EPI_GELU 2

template <int EPI>
__launch_bounds__(512, 2)
__global__ void gemm8(const unsigned short* __restrict__ A,
                      const unsigned short* __restrict__ W,
                      const float* __restrict__ bias,
                      const float* __restrict__ resid,
                      void* __restrict__ out0,
                      unsigned short* __restrict__ q_out,
                      unsigned short* __restrict__ k_out,
                      unsigned short* __restrict__ v_out,
                      int M, int N, int K, int NB) {
    __shared__ __align__(16) unsigned short lds[2][2][256][64];
    const int tid = threadIdx.x;
    const int lane = tid & 63;
    const int wid = tid >> 6;
    const int wm = wid >> 2, wn = wid & 3;
    const int rl = lane & 15, kg = lane >> 4;

    // bijective XCD swizzle (m204), bn-fastest so chunk-mates share the A panel
    const int nwg = gridDim.x;
    const int orig = blockIdx.x;
    const int xcd = orig & 7;
    const int qq = nwg >> 3, rr = nwg & 7;
    const int wg = (xcd < rr ? xcd * (qq + 1) : rr * (qq + 1) + (xcd - rr) * qq) + (orig >> 3);
    const int bm = wg / NB, bn = wg - bm * NB;

    const int NT = K >> 6;

    auto stage = [&](int t, int X, int h) {
        const unsigned short* src = (X == 0) ? A : W;
        const int pb = ((X == 0) ? bm : bn) * 256 + h * 128;
        unsigned short* dst = &lds[t & 1][X][h * 128][0];
#pragma unroll
        for (int j = 0; j < 2; ++j) {
            const int c = j * 512 + tid;      // 1024 chunks x 16B = 16KB half-tile
            const int rw = c >> 3, sl = c & 7;
            const int ssl = sl ^ (rw & 7);    // inverse swizzle on global source
            int rg = pb + rw;
            if (X == 0 && rg >= M) rg = M - 1;
            gld16(dst + c * 8, src + (size_t)rg * K + t * 64 + ssl * 8);
        }
    };

    f32x4 acc[8][4];
#pragma unroll
    for (int m = 0; m < 8; ++m)
#pragma unroll
        for (int n = 0; n < 4; ++n) acc[m][n] = f32x4{0.f, 0.f, 0.f, 0.f};

    // prologue: K0 fully + A halves of K1; vmcnt(4) leaves A(1) in flight
    stage(0, 0, 0); stage(0, 0, 1); stage(0, 1, 0); stage(0, 1, 1);
    stage(1, 0, 0); stage(1, 0, 1);
    asm volatile("s_waitcnt vmcnt(4)" ::: "memory");
    BAR();

    for (int t = 0; t < NT; ++t) {
        const int buf = t & 1;
        sv8 af[8][2], bf[4][2];
        // -------- phase 1: read af[0..3], bf[0..1]; stage B_lo(t+1); MFMA Q(00)
#pragma unroll
        for (int m = 0; m < 4; ++m)
#pragma unroll
            for (int ks = 0; ks < 2; ++ks)
                af[m][ks] = *(const sv8*)&lds[buf][0][wm * 128 + m * 16 + rl][(((ks << 2) | kg) ^ (rl & 7)) << 3];
#pragma unroll
        for (int n = 0; n < 2; ++n)
#pragma unroll
            for (int ks = 0; ks < 2; ++ks)
                bf[n][ks] = *(const sv8*)&lds[buf][1][wn * 64 + n * 16 + rl][(((ks << 2) | kg) ^ (rl & 7)) << 3];
        if (t + 1 < NT) stage(t + 1, 1, 0);
        BAR();
        LGKM0(); SCHED();
        __builtin_amdgcn_s_setprio(1);
#pragma unroll
        for (int m = 0; m < 4; ++m)
#pragma unroll
            for (int n = 0; n < 2; ++n)
#pragma unroll
                for (int ks = 0; ks < 2; ++ks)
                    acc[m][n] = mfma16(af[m][ks], bf[n][ks], acc[m][n]);
        __builtin_amdgcn_s_setprio(0); SCHED();
        BAR();
        // -------- phase 2: read af[4..7]; stage B_hi(t+1); MFMA Q(10)
#pragma unroll
        for (int m = 4; m < 8; ++m)
#pragma unroll
            for (int ks = 0; ks < 2; ++ks)
                af[m][ks] = *(const sv8*)&lds[buf][0][wm * 128 + m * 16 + rl][(((ks << 2) | kg) ^ (rl & 7)) << 3];
        if (t + 1 < NT) stage(t + 1, 1, 1);
        BAR();
        LGKM0(); SCHED();
        __builtin_amdgcn_s_setprio(1);
#pragma unroll
        for (int m = 4; m < 8; ++m)
#pragma unroll
            for (int n = 0; n < 2; ++n)
#pragma unroll
                for (int ks = 0; ks < 2; ++ks)
                    acc[m][n] = mfma16(af[m][ks], bf[n][ks], acc[m][n]);
        __builtin_amdgcn_s_setprio(0); SCHED();
        BAR();
        // -------- phase 3: read bf[2..3]; stage A_lo(t+2); MFMA Q(01)
#pragma unroll
        for (int n = 2; n < 4; ++n)
#pragma unroll
            for (int ks = 0; ks < 2; ++ks)
                bf[n][ks] = *(const sv8*)&lds[buf][1][wn * 64 + n * 16 + rl][(((ks << 2) | kg) ^ (rl & 7)) << 3];
        if (t + 2 < NT) stage(t + 2, 0, 0);
        BAR();
        LGKM0(); SCHED();
        __builtin_amdgcn_s_setprio(1);
#pragma unroll
        for (int m = 0; m < 4; ++m)
#pragma unroll
            for (int n = 2; n < 4; ++n)
#pragma unroll
                for (int ks = 0; ks < 2; ++ks)
                    acc[m][n] = mfma16(af[m][ks], bf[n][ks], acc[m][n]);
        __builtin_amdgcn_s_setprio(0); SCHED();
        BAR();
        // -------- phase 4: stage A_hi(t+2); counted vmcnt; MFMA Q(11)
        if (t + 2 < NT) {
            stage(t + 2, 0, 1);
            asm volatile("s_waitcnt vmcnt(4)" ::: "memory");   // leaves A(t+2) in flight
        } else if (t + 1 < NT) {
            asm volatile("s_waitcnt vmcnt(0)" ::: "memory");   // epilogue drain
        }
        BAR();
        __builtin_amdgcn_s_setprio(1);
#pragma unroll
        for (int m = 4; m < 8; ++m)
#pragma unroll
            for (int n = 2; n < 4; ++n)
#pragma unroll
                for (int ks = 0; ks < 2; ++ks)
                    acc[m][n] = mfma16(af[m][ks], bf[n][ks], acc[m][n]);
        __builtin_amdgcn_s_setprio(0); SCHED();
        BAR();
    }

    // epilogue: C/D layout col=lane&15, row=(lane>>4)*4+reg (m89-verified)
#pragma unroll
    for (int m = 0; m < 8; ++m) {
        const int gm0 = bm * 256 + wm * 128 + m * 16 + kg * 4;
#pragma unroll
        for (int n = 0; n < 4; ++n) {
            const int ncol = bn * 256 + wn * 64 + n * 16 + rl;
            const float bia = bias[ncol];
#pragma unroll
            for (int r = 0; r < 4; ++r) {
                const int mm = gm0 + r;
                if (mm >= M) continue;
                float vv = acc[m][n][r] + bia;
                if constexpr (EPI == EPI_QKV) {
                    int b = mm / 197, nn = mm - b * 197;
                    int which = ncol / 768;
                    int rc = ncol - which * 768;
                    int h = rc >> 6;
                    int d = ncol & 63;
                    if (which == 0)
                        q_out[(((size_t)(b * 12 + h) * 197 + nn) << 6) + d] = f2bf(vv);
                    else if (which == 1)
                        k_out[(((size_t)(b * 12 + h) * 224 + 20 + nn) << 6) + d] = f2bf(vv);
                    else
                        v_out[((size_t)(b * 12 + h) * 64 + d) * 224 + 20 + nn] = f2bf(vv);
                } else if constexpr (EPI == EPI_RES) {
                    ((float*)out0)[(size_t)mm * N + ncol] = vv + resid[(size_t)mm * N + ncol];
                } else {  // GELU exact
                    float g = 0.5f * vv * (1.0f + erff(vv * 0.70710678118f));
                    ((unsigned short*)out0)[(size_t)mm * N + ncol] = f2bf(g);
                }
            }
        }
    }
}

// ---------------- attention: per (b,h,qtile64): S=QK^T, softmax, O=PV ----------------

__global__ void attn_kernel(const unsigned short* __restrict__ Qg,
                            const unsigned short* __restrict__ Kg,
                            const unsigned short* __restrict__ Vtg,
                            unsigned short* __restrict__ obuf) {
    __shared__ __align__(16) unsigned short sKS[14848];  // max(224*64, 4*16*232)
    __shared__ __align__(16) unsigned short sV[64 * 232];
    const int tid = threadIdx.x;
    const int lane = tid & 63;
    const int wave = tid >> 6;
    const int rl = lane & 15, kg = lane >> 4;
    const int qt = blockIdx.x, h = blockIdx.y, b = blockIdx.z;
    const size_t bh = (size_t)b * 12 + h;
    const size_t qbase = bh * 197 * 64;
    const size_t kbase = bh * 224 * 64;
    const size_t vbase = bh * 64 * 224;

    int qrow = qt * 64 + wave * 16 + rl;
    if (qrow > 196) qrow = 196;
    sv8 qf[2];
#pragma unroll
    for (int ks = 0; ks < 2; ++ks)
        qf[ks] = *reinterpret_cast<const sv8*>(&Qg[qbase + (size_t)qrow * 64 + ks * 32 + kg * 8]);

#pragma unroll
    for (int i = 0; i < 7; ++i) {
        const int c = i * 256 + tid;       // 1792 chunks of 16B
        const int key = c >> 3, sl = c & 7;
        const int ssl = sl ^ (key & 7);
        gld16(&sKS[c * 8], &Kg[kbase + key * 64 + ssl * 8]);
    }
#pragma unroll
    for (int i = 0; i < 7; ++i) {
        const int c = i * 256 + tid;
        const int d = c / 28, sl = c - d * 28;
        sv8 val = *reinterpret_cast<const sv8*>(&Vtg[vbase + d * 224 + sl * 8]);
        *reinterpret_cast<sv8*>(&sV[d * 232 + sl * 8]) = val;
    }
    __syncthreads();

    f32x4 sacc[14];
#pragma unroll
    for (int f = 0; f < 14; ++f) sacc[f] = f32x4{0.f, 0.f, 0.f, 0.f};
#pragma unroll
    for (int f = 0; f < 14; ++f) {
        const int key = f * 16 + rl;
#pragma unroll
        for (int ks = 0; ks < 2; ++ks) {
            const int sl = (ks * 4 + kg) ^ (key & 7);
            sv8 kf = *reinterpret_cast<const sv8*>(&sKS[key * 64 + sl * 8]);
            sacc[f] = mfma16(qf[ks], kf, sacc[f]);
        }
    }

    float mx[4] = {-1e30f, -1e30f, -1e30f, -1e30f};
#pragma unroll
    for (int f = 0; f < 14; ++f) {
        const int col = f * 16 + rl;
#pragma unroll
        for (int r = 0; r < 4; ++r) {
            float s = sacc[f][r] * 0.125f;
            if (col >= 217) s = -1e30f;
            sacc[f][r] = s;
            mx[r] = fmaxf(mx[r], s);
        }
    }
#pragma unroll
    for (int o = 1; o < 16; o <<= 1)
#pragma unroll
        for (int r = 0; r < 4; ++r) mx[r] = fmaxf(mx[r], __shfl_xor(mx[r], o));
    float sm[4] = {0.f, 0.f, 0.f, 0.f};
#pragma unroll
    for (int f = 0; f < 14; ++f)
#pragma unroll
        for (int r = 0; r < 4; ++r) {
            float e = __expf(sacc[f][r] - mx[r]);
            sacc[f][r] = e;
            sm[r] += e;
        }
#pragma unroll
    for (int o = 1; o < 16; o <<= 1)
#pragma unroll
        for (int r = 0; r < 4; ++r) sm[r] += __shfl_xor(sm[r], o);
    float inv[4];
#pragma unroll
    for (int r = 0; r < 4; ++r) inv[r] = 1.0f / sm[r];

    __syncthreads();
    unsigned short* Sl = sKS;  // S [4 waves][16 q][232]
#pragma unroll
    for (int f = 0; f < 14; ++f)
#pragma unroll
        for (int r = 0; r < 4; ++r)
            Sl[(wave * 16 + kg * 4 + r) * 232 + f * 16 + rl] = f2bf(sacc[f][r] * inv[r]);
    __syncthreads();

    f32x4 oacc[4];
#pragma unroll
    for (int fd = 0; fd < 4; ++fd) oacc[fd] = f32x4{0.f, 0.f, 0.f, 0.f};
#pragma unroll
    for (int ks = 0; ks < 7; ++ks) {
        sv8 pf = *reinterpret_cast<const sv8*>(&Sl[(wave * 16 + rl) * 232 + ks * 32 + kg * 8]);
#pragma unroll
        for (int fd = 0; fd < 4; ++fd) {
            sv8 vf = *reinterpret_cast<const sv8*>(&sV[(fd * 16 + rl) * 232 + ks * 32 + kg * 8]);
            oacc[fd] = mfma16(pf, vf, oacc[fd]);
        }
    }

#pragma unroll
    for (int fd = 0; fd < 4; ++fd)
#pragma unroll
        for (int r = 0; r < 4; ++r) {
            const int q = qt * 64 + wave * 16 + kg * 4 + r;
            if (q < 197)
                obuf[((size_t)b * 197 + q) * 768 + h * 64 + fd * 16 + rl] = f2bf(oacc[fd][r]);
        }
}

// ---------------- host ----------------

extern "C" void kernel_launch(void* const* d_in, const int* in_sizes, int n_in,
                              void* d_out, int out_size, void* d_ws, size_t ws_size,
                              hipStream_t stream) {
    const float* x      = (const float*)d_in[0];
    const float* prompt = (const float*)d_in[1];
    const float* ln1_w  = (const float*)d_in[2];
    const float* ln1_b  = (const float*)d_in[3];
    const float* qkv_w  = (const float*)d_in[4];
    const float* qkv_b  = (const float*)d_in[5];
    const float* proj_w = (const float*)d_in[6];
    const float* proj_b = (const float*)d_in[7];
    const float* ln2_w  = (const float*)d_in[8];
    const float* ln2_b  = (const float*)d_in[9];
    const float* fc1_w  = (const float*)d_in[10];
    const float* fc1_b  = (const float*)d_in[11];
    const float* fc2_w  = (const float*)d_in[12];
    const float* fc2_b  = (const float*)d_in[13];

    char* ws = (char*)d_ws;
    size_t off = 0;
    auto bump = [&](size_t bytes) {
        char* p = ws + off;
        off += (bytes + 255) & ~(size_t)255;
        return p;
    };
    unsigned short* qkvw  = (unsigned short*)bump(2304UL * 768 * 2);
    unsigned short* projw = (unsigned short*)bump(768UL * 768 * 2);
    unsigned short* fc1w  = (unsigned short*)bump(3072UL * 768 * 2);
    unsigned short* fc2w  = (unsigned short*)bump(768UL * 3072 * 2);
    unsigned short* h2    = (unsigned short*)bump(12608UL * 768 * 2);
    float* xmid           = (float*)bump(12608UL * 768 * 4);
    char* pool = ws + off;
    unsigned short* h1   = (unsigned short*)(pool);
    unsigned short* Qg   = (unsigned short*)(pool + 19365888UL);
    unsigned short* Kg   = (unsigned short*)(pool + 38731776UL);
    unsigned short* Vtg  = (unsigned short*)(pool + 60751872UL);
    unsigned short* obuf = (unsigned short*)(pool + 82771968UL);
    unsigned short* mbuf = (unsigned short*)(pool);  // aliases h1/Q/K/Vt (dead by fc1)

    cvt_bf16_kernel<<<(2304 * 768 / 4 + 255) / 256, 256, 0, stream>>>(qkv_w, qkvw, 2304 * 768 / 4);
    cvt_bf16_kernel<<<(768 * 768 / 4 + 255) / 256, 256, 0, stream>>>(proj_w, projw, 768 * 768 / 4);
    cvt_bf16_kernel<<<(3072 * 768 / 4 + 255) / 256, 256, 0, stream>>>(fc1_w, fc1w, 3072 * 768 / 4);
    cvt_bf16_kernel<<<(768 * 3072 / 4 + 255) / 256, 256, 0, stream>>>(fc2_w, fc2w, 768 * 3072 / 4);

    ln_kernel<<<12608, 256, 0, stream>>>(x, ln1_w, ln1_b, h1);
    prompt_kernel<<<983040 / 256, 256, 0, stream>>>(prompt, Kg, Vtg);

    // qkv: M=12608 (50 m-blocks), N=2304 (9 n-blocks), K=768
    gemm8<EPI_QKV><<<50 * 9, 512, 0, stream>>>(
        h1, qkvw, qkv_b, nullptr, nullptr, Qg, Kg, Vtg, 12608, 2304, 768, 9);

    attn_kernel<<<dim3(4, 12, 64), 256, 0, stream>>>(Qg, Kg, Vtg, obuf);

    // proj: N=768 (3 n-blocks), K=768
    gemm8<EPI_RES><<<50 * 3, 512, 0, stream>>>(
        obuf, projw, proj_b, x, xmid, nullptr, nullptr, nullptr, 12608, 768, 768, 3);

    ln_kernel<<<12608, 256, 0, stream>>>(xmid, ln2_w, ln2_b, h2);

    // fc1: N=3072 (12 n-blocks), K=768
    gemm8<EPI_GELU><<<50 * 12, 512, 0, stream>>>(
        h2, fc1w, fc1_b, nullptr, mbuf, nullptr, nullptr, nullptr, 12608, 3072, 768, 12);

    // fc2: N=768 (3 n-blocks), K=3072
    gemm8<EPI_RES><<<50 * 3, 512, 0, stream>>>(
        mbuf, fc2w, fc2_b, xmid, (float*)d_out, nullptr, nullptr, nullptr, 12608, 768, 3072, 3);
}

// Round 4
// 444.739 us; speedup vs baseline: 1.5219x; 1.5219x over previous
//
#include <hip/hip_runtime.h>
#include <hip/hip_bf16.h>

typedef __attribute__((ext_vector_type(4))) float f32x4;
typedef __attribute__((ext_vector_type(8))) __bf16 bfv8;
typedef __attribute__((ext_vector_type(8))) short sv8;
typedef __attribute__((ext_vector_type(4))) unsigned short usv4;

// ---------------- helpers ----------------

static __device__ __forceinline__ f32x4 mfma16(sv8 a, sv8 b, f32x4 c) {
    return __builtin_amdgcn_mfma_f32_16x16x32_bf16(
        __builtin_bit_cast(bfv8, a), __builtin_bit_cast(bfv8, b), c, 0, 0, 0);
}

static __device__ __forceinline__ unsigned short f2bf(float f) {
    union { float f; unsigned int u; } v; v.f = f;
    unsigned int u = v.u;
    return (unsigned short)((u + 0x7FFFu + ((u >> 16) & 1u)) >> 16);  // RNE
}

// async global->LDS, 16B per lane (dest linear in lane order)
static __device__ __forceinline__ void gld16(void* lds, const void* g) {
    __builtin_amdgcn_global_load_lds(
        (const __attribute__((address_space(1))) unsigned int*)g,
        (__attribute__((address_space(3))) unsigned int*)lds, 16, 0, 0);
}

// ---------------- fp32 -> bf16 convert (weights) ----------------

__global__ void cvt_bf16_kernel(const float* __restrict__ in,
                                unsigned short* __restrict__ out, int n4) {
    int i = blockIdx.x * 256 + threadIdx.x;
    if (i >= n4) return;
    float4 f = reinterpret_cast<const float4*>(in)[i];
    usv4 o = { f2bf(f.x), f2bf(f.y), f2bf(f.z), f2bf(f.w) };
    reinterpret_cast<usv4*>(out)[i] = o;
}

// ---------------- LayerNorm fp32 -> bf16, C=768 ----------------

__global__ void ln_kernel(const float* __restrict__ x, const float* __restrict__ w,
                          const float* __restrict__ b, unsigned short* __restrict__ out) {
    const int row = blockIdx.x;
    const int t = threadIdx.x;
    const float* xr = x + (size_t)row * 768;
    float v[3];
    float s = 0.f, ss = 0.f;
#pragma unroll
    for (int i = 0; i < 3; ++i) {
        v[i] = xr[t + i * 256];
        s += v[i]; ss += v[i] * v[i];
    }
#pragma unroll
    for (int o = 32; o; o >>= 1) { s += __shfl_xor(s, o); ss += __shfl_xor(ss, o); }
    __shared__ float red[8];
    if ((t & 63) == 0) { red[t >> 6] = s; red[4 + (t >> 6)] = ss; }
    __syncthreads();
    float S = red[0] + red[1] + red[2] + red[3];
    float SS = red[4] + red[5] + red[6] + red[7];
    float mu = S * (1.0f / 768.0f);
    float var = SS * (1.0f / 768.0f) - mu * mu;
    float rstd = rsqrtf(var + 1e-6f);
#pragma unroll
    for (int i = 0; i < 3; ++i) {
        int c = t + i * 256;
        out[(size_t)row * 768 + c] = f2bf((v[i] - mu) * rstd * w[c] + b[c]);
    }
}

// ---------------- prompt [B,20,2,H,64] fp32 -> K [B,H,224,64], Vt [B,H,64,224] bf16 ----------------

__global__ void prompt_kernel(const float* __restrict__ pr,
                              unsigned short* __restrict__ k_out,
                              unsigned short* __restrict__ v_out) {
    int i = blockIdx.x * 256 + threadIdx.x;  // over B*P*H*64 = 983040
    if (i >= 64 * 20 * 12 * 64) return;
    int d = i & 63;
    int t = i >> 6;
    int h = t % 12;
    int t2 = t / 12;
    int p = t2 % 20;
    int b = t2 / 20;
    size_t src = ((((size_t)b * 20 + p) * 2 + 0) * 12 + h) * 64 + d;
    float kv = pr[src];
    float vv = pr[src + 12 * 64];  // s=1 plane
    k_out[(((size_t)(b * 12 + h) * 224 + p) << 6) + d] = f2bf(kv);
    v_out[((size_t)(b * 12 + h) * 64 + d) * 224 + p] = f2bf(vv);
}

// ---------------- bf16 GEMM: C[M,N] = A[M,K] @ W[N,K]^T, fused epilogues ----------------
// Round-2 proven body: 128x128 tile, BK=32, 4 waves (2x2), 16 KB LDS -> ~8 blocks/CU (TLP
// hides load latency; round-3's 1-block/CU deep pipeline was latency-bound at 10% MfmaUtil).
// Round-3 proven grid mapping kept: 1-D grid, bijective XCD swizzle (m204), bn-fastest so
// the resident blocks of one XCD share few A-panels x all W-columns (FETCH 242->68 MB).

#define EPI_QKV 0
#define EPI_RES 1
#define EPI_GELU 2

template <int EPI>
__global__ void gemm_bf16(const unsigned short* __restrict__ A,
                          const unsigned short* __restrict__ W,
                          const float* __restrict__ bias,
                          const float* __restrict__ resid,
                          void* __restrict__ out0,
                          unsigned short* __restrict__ q_out,
                          unsigned short* __restrict__ k_out,
                          unsigned short* __restrict__ v_out,
                          int M, int N, int K, int NB) {
    __shared__ __align__(16) unsigned short As[128 * 32];
    __shared__ __align__(16) unsigned short Bs[128 * 32];
    const int tid = threadIdx.x;
    const int lane = tid & 63;
    const int wave = tid >> 6;
    const int wm = wave >> 1, wn = wave & 1;
    const int rl = lane & 15, kg = lane >> 4;

    // bijective XCD swizzle (m204); wg increases bn-fastest (bm = wg/NB)
    const int nwg = gridDim.x;
    const int orig = blockIdx.x;
    const int xcd = orig & 7;
    const int qq = nwg >> 3, rr = nwg & 7;
    const int wg = (xcd < rr ? xcd * (qq + 1) : rr * (qq + 1) + (xcd - rr) * qq) + (orig >> 3);
    const int bm = wg / NB, bn = wg - bm * NB;

    f32x4 acc[4][4];
#pragma unroll
    for (int i = 0; i < 4; ++i)
#pragma unroll
        for (int j = 0; j < 4; ++j) acc[i][j] = f32x4{0.f, 0.f, 0.f, 0.f};

    const int nk = K >> 5;
    for (int kt = 0; kt < nk; ++kt) {
        const int k0 = kt << 5;
#pragma unroll
        for (int i = 0; i < 2; ++i) {
            const int c = i * 256 + tid;
            const int row = c >> 2, sl = c & 3;
            const int ss = sl ^ ((row >> 1) & 3);  // XOR swizzle (inverse on source)
            int ar = bm * 128 + row; ar = ar < M ? ar : M - 1;
            gld16(&As[c * 8], &A[(size_t)ar * K + k0 + ss * 8]);
            gld16(&Bs[c * 8], &W[(size_t)(bn * 128 + row) * K + k0 + ss * 8]);
        }
        __syncthreads();
        sv8 af[4], bfr[4];
#pragma unroll
        for (int f = 0; f < 4; ++f) {
            const int ra = wm * 64 + f * 16 + rl;
            af[f] = *reinterpret_cast<const sv8*>(&As[ra * 32 + (kg ^ ((ra >> 1) & 3)) * 8]);
            const int rb = wn * 64 + f * 16 + rl;
            bfr[f] = *reinterpret_cast<const sv8*>(&Bs[rb * 32 + (kg ^ ((rb >> 1) & 3)) * 8]);
        }
#pragma unroll
        for (int i = 0; i < 4; ++i)
#pragma unroll
            for (int j = 0; j < 4; ++j) acc[i][j] = mfma16(af[i], bfr[j], acc[i][j]);
        __syncthreads();
    }

    // epilogue: C/D layout col=lane&15, row=(lane>>4)*4+reg (m89-verified)
#pragma unroll
    for (int i = 0; i < 4; ++i) {
        const int m0 = bm * 128 + wm * 64 + i * 16 + kg * 4;
#pragma unroll
        for (int j = 0; j < 4; ++j) {
            const int ncol = bn * 128 + wn * 64 + j * 16 + rl;
            const float bia = bias[ncol];
#pragma unroll
            for (int r = 0; r < 4; ++r) {
                const int m = m0 + r;
                if (m >= M) continue;
                float vv = acc[i][j][r] + bia;
                if constexpr (EPI == EPI_QKV) {
                    int b = m / 197, nn = m - b * 197;
                    int which = ncol / 768;
                    int rc = ncol - which * 768;
                    int h = rc >> 6;
                    int d = ncol & 63;
                    if (which == 0)
                        q_out[(((size_t)(b * 12 + h) * 197 + nn) << 6) + d] = f2bf(vv);
                    else if (which == 1)
                        k_out[(((size_t)(b * 12 + h) * 224 + 20 + nn) << 6) + d] = f2bf(vv);
                    else
                        v_out[((size_t)(b * 12 + h) * 64 + d) * 224 + 20 + nn] = f2bf(vv);
                } else if constexpr (EPI == EPI_RES) {
                    ((float*)out0)[(size_t)m * N + ncol] = vv + resid[(size_t)m * N + ncol];
                } else {  // GELU exact
                    float g = 0.5f * vv * (1.0f + erff(vv * 0.70710678118f));
                    ((unsigned short*)out0)[(size_t)m * N + ncol] = f2bf(g);
                }
            }
        }
    }
}

// ---------------- attention: per (b,h,qtile64): S=QK^T, softmax, O=PV ----------------

__global__ void attn_kernel(const unsigned short* __restrict__ Qg,
                            const unsigned short* __restrict__ Kg,
                            const unsigned short* __restrict__ Vtg,
                            unsigned short* __restrict__ obuf) {
    __shared__ __align__(16) unsigned short sKS[14848];  // max(224*64, 4*16*232)
    __shared__ __align__(16) unsigned short sV[64 * 232];
    const int tid = threadIdx.x;
    const int lane = tid & 63;
    const int wave = tid >> 6;
    const int rl = lane & 15, kg = lane >> 4;
    const int qt = blockIdx.x, h = blockIdx.y, b = blockIdx.z;
    const size_t bh = (size_t)b * 12 + h;
    const size_t qbase = bh * 197 * 64;
    const size_t kbase = bh * 224 * 64;
    const size_t vbase = bh * 64 * 224;

    int qrow = qt * 64 + wave * 16 + rl;
    if (qrow > 196) qrow = 196;
    sv8 qf[2];
#pragma unroll
    for (int ks = 0; ks < 2; ++ks)
        qf[ks] = *reinterpret_cast<const sv8*>(&Qg[qbase + (size_t)qrow * 64 + ks * 32 + kg * 8]);

#pragma unroll
    for (int i = 0; i < 7; ++i) {
        const int c = i * 256 + tid;       // 1792 chunks of 16B
        const int key = c >> 3, sl = c & 7;
        const int ssl = sl ^ (key & 7);
        gld16(&sKS[c * 8], &Kg[kbase + key * 64 + ssl * 8]);
    }
#pragma unroll
    for (int i = 0; i < 7; ++i) {
        const int c = i * 256 + tid;
        const int d = c / 28, sl = c - d * 28;
        sv8 val = *reinterpret_cast<const sv8*>(&Vtg[vbase + d * 224 + sl * 8]);
        *reinterpret_cast<sv8*>(&sV[d * 232 + sl * 8]) = val;
    }
    __syncthreads();

    f32x4 sacc[14];
#pragma unroll
    for (int f = 0; f < 14; ++f) sacc[f] = f32x4{0.f, 0.f, 0.f, 0.f};
#pragma unroll
    for (int f = 0; f < 14; ++f) {
        const int key = f * 16 + rl;
#pragma unroll
        for (int ks = 0; ks < 2; ++ks) {
            const int sl = (ks * 4 + kg) ^ (key & 7);
            sv8 kf = *reinterpret_cast<const sv8*>(&sKS[key * 64 + sl * 8]);
            sacc[f] = mfma16(qf[ks], kf, sacc[f]);
        }
    }

    float mx[4] = {-1e30f, -1e30f, -1e30f, -1e30f};
#pragma unroll
    for (int f = 0; f < 14; ++f) {
        const int col = f * 16 + rl;
#pragma unroll
        for (int r = 0; r < 4; ++r) {
            float s = sacc[f][r] * 0.125f;
            if (col >= 217) s = -1e30f;
            sacc[f][r] = s;
            mx[r] = fmaxf(mx[r], s);
        }
    }
#pragma unroll
    for (int o = 1; o < 16; o <<= 1)
#pragma unroll
        for (int r = 0; r < 4; ++r) mx[r] = fmaxf(mx[r], __shfl_xor(mx[r], o));
    float sm[4] = {0.f, 0.f, 0.f, 0.f};
#pragma unroll
    for (int f = 0; f < 14; ++f)
#pragma unroll
        for (int r = 0; r < 4; ++r) {
            float e = __expf(sacc[f][r] - mx[r]);
            sacc[f][r] = e;
            sm[r] += e;
        }
#pragma unroll
    for (int o = 1; o < 16; o <<= 1)
#pragma unroll
        for (int r = 0; r < 4; ++r) sm[r] += __shfl_xor(sm[r], o);
    float inv[4];
#pragma unroll
    for (int r = 0; r < 4; ++r) inv[r] = 1.0f / sm[r];

    __syncthreads();
    unsigned short* Sl = sKS;  // S [4 waves][16 q][232]
#pragma unroll
    for (int f = 0; f < 14; ++f)
#pragma unroll
        for (int r = 0; r < 4; ++r)
            Sl[(wave * 16 + kg * 4 + r) * 232 + f * 16 + rl] = f2bf(sacc[f][r] * inv[r]);
    __syncthreads();

    f32x4 oacc[4];
#pragma unroll
    for (int fd = 0; fd < 4; ++fd) oacc[fd] = f32x4{0.f, 0.f, 0.f, 0.f};
#pragma unroll
    for (int ks = 0; ks < 7; ++ks) {
        sv8 pf = *reinterpret_cast<const sv8*>(&Sl[(wave * 16 + rl) * 232 + ks * 32 + kg * 8]);
#pragma unroll
        for (int fd = 0; fd < 4; ++fd) {
            sv8 vf = *reinterpret_cast<const sv8*>(&sV[(fd * 16 + rl) * 232 + ks * 32 + kg * 8]);
            oacc[fd] = mfma16(pf, vf, oacc[fd]);
        }
    }

#pragma unroll
    for (int fd = 0; fd < 4; ++fd)
#pragma unroll
        for (int r = 0; r < 4; ++r) {
            const int q = qt * 64 + wave * 16 + kg * 4 + r;
            if (q < 197)
                obuf[((size_t)b * 197 + q) * 768 + h * 64 + fd * 16 + rl] = f2bf(oacc[fd][r]);
        }
}

// ---------------- host ----------------

extern "C" void kernel_launch(void* const* d_in, const int* in_sizes, int n_in,
                              void* d_out, int out_size, void* d_ws, size_t ws_size,
                              hipStream_t stream) {
    const float* x      = (const float*)d_in[0];
    const float* prompt = (const float*)d_in[1];
    const float* ln1_w  = (const float*)d_in[2];
    const float* ln1_b  = (const float*)d_in[3];
    const float* qkv_w  = (const float*)d_in[4];
    const float* qkv_b  = (const float*)d_in[5];
    const float* proj_w = (const float*)d_in[6];
    const float* proj_b = (const float*)d_in[7];
    const float* ln2_w  = (const float*)d_in[8];
    const float* ln2_b  = (const float*)d_in[9];
    const float* fc1_w  = (const float*)d_in[10];
    const float* fc1_b  = (const float*)d_in[11];
    const float* fc2_w  = (const float*)d_in[12];
    const float* fc2_b  = (const float*)d_in[13];

    char* ws = (char*)d_ws;
    size_t off = 0;
    auto bump = [&](size_t bytes) {
        char* p = ws + off;
        off += (bytes + 255) & ~(size_t)255;
        return p;
    };
    unsigned short* qkvw  = (unsigned short*)bump(2304UL * 768 * 2);
    unsigned short* projw = (unsigned short*)bump(768UL * 768 * 2);
    unsigned short* fc1w  = (unsigned short*)bump(3072UL * 768 * 2);
    unsigned short* fc2w  = (unsigned short*)bump(768UL * 3072 * 2);
    unsigned short* h2    = (unsigned short*)bump(12608UL * 768 * 2);
    float* xmid           = (float*)bump(12608UL * 768 * 4);
    char* pool = ws + off;
    unsigned short* h1   = (unsigned short*)(pool);
    unsigned short* Qg   = (unsigned short*)(pool + 19365888UL);
    unsigned short* Kg   = (unsigned short*)(pool + 38731776UL);
    unsigned short* Vtg  = (unsigned short*)(pool + 60751872UL);
    unsigned short* obuf = (unsigned short*)(pool + 82771968UL);
    unsigned short* mbuf = (unsigned short*)(pool);  // aliases h1/Q/K/Vt (dead by fc1)

    cvt_bf16_kernel<<<(2304 * 768 / 4 + 255) / 256, 256, 0, stream>>>(qkv_w, qkvw, 2304 * 768 / 4);
    cvt_bf16_kernel<<<(768 * 768 / 4 + 255) / 256, 256, 0, stream>>>(proj_w, projw, 768 * 768 / 4);
    cvt_bf16_kernel<<<(3072 * 768 / 4 + 255) / 256, 256, 0, stream>>>(fc1_w, fc1w, 3072 * 768 / 4);
    cvt_bf16_kernel<<<(768 * 3072 / 4 + 255) / 256, 256, 0, stream>>>(fc2_w, fc2w, 768 * 3072 / 4);

    ln_kernel<<<12608, 256, 0, stream>>>(x, ln1_w, ln1_b, h1);
    prompt_kernel<<<983040 / 256, 256, 0, stream>>>(prompt, Kg, Vtg);

    // qkv: 99 m-blocks x 18 n-blocks
    gemm_bf16<EPI_QKV><<<99 * 18, 256, 0, stream>>>(
        h1, qkvw, qkv_b, nullptr, nullptr, Qg, Kg, Vtg, 12608, 2304, 768, 18);

    attn_kernel<<<dim3(4, 12, 64), 256, 0, stream>>>(Qg, Kg, Vtg, obuf);

    // proj: 99 x 6
    gemm_bf16<EPI_RES><<<99 * 6, 256, 0, stream>>>(
        obuf, projw, proj_b, x, xmid, nullptr, nullptr, nullptr, 12608, 768, 768, 6);

    ln_kernel<<<12608, 256, 0, stream>>>(xmid, ln2_w, ln2_b, h2);

    // fc1: 99 x 24
    gemm_bf16<EPI_GELU><<<99 * 24, 256, 0, stream>>>(
        h2, fc1w, fc1_b, nullptr, mbuf, nullptr, nullptr, nullptr, 12608, 3072, 768, 24);

    // fc2: 99 x 6, K=3072
    gemm_bf16<EPI_RES><<<99 * 6, 256, 0, stream>>>(
        mbuf, fc2w, fc2_b, xmid, (float*)d_out, nullptr, nullptr, nullptr, 12608, 768, 3072, 6);
}

// Round 5
// 421.685 us; speedup vs baseline: 1.6051x; 1.0547x over previous
//
#include <hip/hip_runtime.h>
#include <hip/hip_bf16.h>

typedef __attribute__((ext_vector_type(4))) float f32x4;
typedef __attribute__((ext_vector_type(8))) __bf16 bfv8;
typedef __attribute__((ext_vector_type(8))) short sv8;
typedef __attribute__((ext_vector_type(4))) unsigned short usv4;

// ---------------- helpers ----------------

static __device__ __forceinline__ f32x4 mfma16(sv8 a, sv8 b, f32x4 c) {
    return __builtin_amdgcn_mfma_f32_16x16x32_bf16(
        __builtin_bit_cast(bfv8, a), __builtin_bit_cast(bfv8, b), c, 0, 0, 0);
}

static __device__ __forceinline__ unsigned short f2bf(float f) {
    union { float f; unsigned int u; } v; v.f = f;
    unsigned int u = v.u;
    return (unsigned short)((u + 0x7FFFu + ((u >> 16) & 1u)) >> 16);  // RNE
}

// async global->LDS, 16B per lane (dest linear in lane order)
static __device__ __forceinline__ void gld16(void* lds, const void* g) {
    __builtin_amdgcn_global_load_lds(
        (const __attribute__((address_space(1))) unsigned int*)g,
        (__attribute__((address_space(3))) unsigned int*)lds, 16, 0, 0);
}

// ---------------- fp32 -> bf16 convert (weights) ----------------

__global__ void cvt_bf16_kernel(const float* __restrict__ in,
                                unsigned short* __restrict__ out, int n4) {
    int i = blockIdx.x * 256 + threadIdx.x;
    if (i >= n4) return;
    float4 f = reinterpret_cast<const float4*>(in)[i];
    usv4 o = { f2bf(f.x), f2bf(f.y), f2bf(f.z), f2bf(f.w) };
    reinterpret_cast<usv4*>(out)[i] = o;
}

// ---------------- LayerNorm fp32 -> bf16, C=768 ----------------

__global__ void ln_kernel(const float* __restrict__ x, const float* __restrict__ w,
                          const float* __restrict__ b, unsigned short* __restrict__ out) {
    const int row = blockIdx.x;
    const int t = threadIdx.x;
    const float* xr = x + (size_t)row * 768;
    float v[3];
    float s = 0.f, ss = 0.f;
#pragma unroll
    for (int i = 0; i < 3; ++i) {
        v[i] = xr[t + i * 256];
        s += v[i]; ss += v[i] * v[i];
    }
#pragma unroll
    for (int o = 32; o; o >>= 1) { s += __shfl_xor(s, o); ss += __shfl_xor(ss, o); }
    __shared__ float red[8];
    if ((t & 63) == 0) { red[t >> 6] = s; red[4 + (t >> 6)] = ss; }
    __syncthreads();
    float S = red[0] + red[1] + red[2] + red[3];
    float SS = red[4] + red[5] + red[6] + red[7];
    float mu = S * (1.0f / 768.0f);
    float var = SS * (1.0f / 768.0f) - mu * mu;
    float rstd = rsqrtf(var + 1e-6f);
#pragma unroll
    for (int i = 0; i < 3; ++i) {
        int c = t + i * 256;
        out[(size_t)row * 768 + c] = f2bf((v[i] - mu) * rstd * w[c] + b[c]);
    }
}

// ---------------- prompt [B,20,2,H,64] fp32 -> K [B,H,224,64], Vt [B,H,64,224] bf16 ----------------

__global__ void prompt_kernel(const float* __restrict__ pr,
                              unsigned short* __restrict__ k_out,
                              unsigned short* __restrict__ v_out) {
    int i = blockIdx.x * 256 + threadIdx.x;  // over B*P*H*64 = 983040
    if (i >= 64 * 20 * 12 * 64) return;
    int d = i & 63;
    int t = i >> 6;
    int h = t % 12;
    int t2 = t / 12;
    int p = t2 % 20;
    int b = t2 / 20;
    size_t src = ((((size_t)b * 20 + p) * 2 + 0) * 12 + h) * 64 + d;
    float kv = pr[src];
    float vv = pr[src + 12 * 64];  // s=1 plane
    k_out[(((size_t)(b * 12 + h) * 224 + p) << 6) + d] = f2bf(kv);
    v_out[((size_t)(b * 12 + h) * 64 + d) * 224 + p] = f2bf(vv);
}

// ---------------- bf16 GEMM: C[M,N] = A[M,K] @ W[N,K]^T, fused epilogues ----------------
// 128x128 tile, BK=32, 4 waves (2x2). 2-PHASE double-buffered LDS (guide T3 minimum):
// stage(t+1) issued at START of iter t -> the end-of-iter __syncthreads' vmcnt(0) drain
// waits on ~300cy-old loads, hidden under ds_read+MFMA of tile t. One barrier per iter.
// Race-free: buf written in iter t was last ds_read in iter t-1; those reads complete
// before the iter-(t-1) barrier (syncthreads waits lgkmcnt per-wave).
// Grid mapping: 1-D grid, bijective XCD swizzle (m204), bn-fastest (FETCH 242->68 MB, r4).

#define EPI_QKV 0
#define EPI_RES 1
#define EPI_GELU 2

template <int EPI>
__global__ void gemm_bf16(const unsigned short* __restrict__ A,
                          const unsigned short* __restrict__ W,
                          const float* __restrict__ bias,
                          const float* __restrict__ resid,
                          void* __restrict__ out0,
                          unsigned short* __restrict__ q_out,
                          unsigned short* __restrict__ k_out,
                          unsigned short* __restrict__ v_out,
                          int M, int N, int K, int NB) {
    __shared__ __align__(16) unsigned short As[2][128 * 32];
    __shared__ __align__(16) unsigned short Bs[2][128 * 32];
    const int tid = threadIdx.x;
    const int lane = tid & 63;
    const int wave = tid >> 6;
    const int wm = wave >> 1, wn = wave & 1;
    const int rl = lane & 15, kg = lane >> 4;

    // bijective XCD swizzle (m204); wg increases bn-fastest (bm = wg/NB)
    const int nwg = gridDim.x;
    const int orig = blockIdx.x;
    const int xcd = orig & 7;
    const int qq = nwg >> 3, rr = nwg & 7;
    const int wg = (xcd < rr ? xcd * (qq + 1) : rr * (qq + 1) + (xcd - rr) * qq) + (orig >> 3);
    const int bm = wg / NB, bn = wg - bm * NB;

    auto stage = [&](int sb, int kt) {
        const int k0 = kt << 5;
#pragma unroll
        for (int i = 0; i < 2; ++i) {
            const int c = i * 256 + tid;
            const int row = c >> 2, sl = c & 3;
            const int ss = sl ^ ((row >> 1) & 3);  // XOR swizzle (inverse on source)
            int ar = bm * 128 + row; ar = ar < M ? ar : M - 1;
            gld16(&As[sb][c * 8], &A[(size_t)ar * K + k0 + ss * 8]);
            gld16(&Bs[sb][c * 8], &W[(size_t)(bn * 128 + row) * K + k0 + ss * 8]);
        }
    };

    f32x4 acc[4][4];
#pragma unroll
    for (int i = 0; i < 4; ++i)
#pragma unroll
        for (int j = 0; j < 4; ++j) acc[i][j] = f32x4{0.f, 0.f, 0.f, 0.f};

    const int nk = K >> 5;
    stage(0, 0);
    __syncthreads();
    for (int kt = 0; kt < nk; ++kt) {
        const int cur = kt & 1;
        if (kt + 1 < nk) stage(cur ^ 1, kt + 1);   // issue next-tile loads EARLY
        sv8 af[4], bfr[4];
#pragma unroll
        for (int f = 0; f < 4; ++f) {
            const int ra = wm * 64 + f * 16 + rl;
            af[f] = *reinterpret_cast<const sv8*>(&As[cur][ra * 32 + (kg ^ ((ra >> 1) & 3)) * 8]);
            const int rb = wn * 64 + f * 16 + rl;
            bfr[f] = *reinterpret_cast<const sv8*>(&Bs[cur][rb * 32 + (kg ^ ((rb >> 1) & 3)) * 8]);
        }
#pragma unroll
        for (int i = 0; i < 4; ++i)
#pragma unroll
            for (int j = 0; j < 4; ++j) acc[i][j] = mfma16(af[i], bfr[j], acc[i][j]);
        __syncthreads();   // drains vmcnt(0) (next buf staged) + lgkm; one barrier/iter
    }

    // epilogue: C/D layout col=lane&15, row=(lane>>4)*4+reg (m89-verified)
#pragma unroll
    for (int i = 0; i < 4; ++i) {
        const int m0 = bm * 128 + wm * 64 + i * 16 + kg * 4;
#pragma unroll
        for (int j = 0; j < 4; ++j) {
            const int ncol = bn * 128 + wn * 64 + j * 16 + rl;
            const float bia = bias[ncol];
#pragma unroll
            for (int r = 0; r < 4; ++r) {
                const int m = m0 + r;
                if (m >= M) continue;
                float vv = acc[i][j][r] + bia;
                if constexpr (EPI == EPI_QKV) {
                    int b = m / 197, nn = m - b * 197;
                    int which = ncol / 768;
                    int rc = ncol - which * 768;
                    int h = rc >> 6;
                    int d = ncol & 63;
                    if (which == 0)
                        q_out[(((size_t)(b * 12 + h) * 197 + nn) << 6) + d] = f2bf(vv);
                    else if (which == 1)
                        k_out[(((size_t)(b * 12 + h) * 224 + 20 + nn) << 6) + d] = f2bf(vv);
                    else
                        v_out[((size_t)(b * 12 + h) * 64 + d) * 224 + 20 + nn] = f2bf(vv);
                } else if constexpr (EPI == EPI_RES) {
                    ((float*)out0)[(size_t)m * N + ncol] = vv + resid[(size_t)m * N + ncol];
                } else {  // GELU tanh-approx in sigmoid form: ~8 VALU ops vs ~25 for erff
                    float g = vv / (1.0f + __expf(-1.5957691216f * vv * (1.0f + 0.044715f * vv * vv)));
                    ((unsigned short*)out0)[(size_t)m * N + ncol] = f2bf(g);
                }
            }
        }
    }
}

// ---------------- attention: per (b,h,qtile64): S=QK^T, softmax, O=PV ----------------

__global__ void attn_kernel(const unsigned short* __restrict__ Qg,
                            const unsigned short* __restrict__ Kg,
                            const unsigned short* __restrict__ Vtg,
                            unsigned short* __restrict__ obuf) {
    __shared__ __align__(16) unsigned short sKS[14848];  // max(224*64, 4*16*232)
    __shared__ __align__(16) unsigned short sV[64 * 232];
    const int tid = threadIdx.x;
    const int lane = tid & 63;
    const int wave = tid >> 6;
    const int rl = lane & 15, kg = lane >> 4;
    const int qt = blockIdx.x, h = blockIdx.y, b = blockIdx.z;
    const size_t bh = (size_t)b * 12 + h;
    const size_t qbase = bh * 197 * 64;
    const size_t kbase = bh * 224 * 64;
    const size_t vbase = bh * 64 * 224;

    int qrow = qt * 64 + wave * 16 + rl;
    if (qrow > 196) qrow = 196;
    sv8 qf[2];
#pragma unroll
    for (int ks = 0; ks < 2; ++ks)
        qf[ks] = *reinterpret_cast<const sv8*>(&Qg[qbase + (size_t)qrow * 64 + ks * 32 + kg * 8]);

#pragma unroll
    for (int i = 0; i < 7; ++i) {
        const int c = i * 256 + tid;       // 1792 chunks of 16B
        const int key = c >> 3, sl = c & 7;
        const int ssl = sl ^ (key & 7);
        gld16(&sKS[c * 8], &Kg[kbase + key * 64 + ssl * 8]);
    }
#pragma unroll
    for (int i = 0; i < 7; ++i) {
        const int c = i * 256 + tid;
        const int d = c / 28, sl = c - d * 28;
        sv8 val = *reinterpret_cast<const sv8*>(&Vtg[vbase + d * 224 + sl * 8]);
        *reinterpret_cast<sv8*>(&sV[d * 232 + sl * 8]) = val;
    }
    __syncthreads();

    f32x4 sacc[14];
#pragma unroll
    for (int f = 0; f < 14; ++f) sacc[f] = f32x4{0.f, 0.f, 0.f, 0.f};
#pragma unroll
    for (int f = 0; f < 14; ++f) {
        const int key = f * 16 + rl;
#pragma unroll
        for (int ks = 0; ks < 2; ++ks) {
            const int sl = (ks * 4 + kg) ^ (key & 7);
            sv8 kf = *reinterpret_cast<const sv8*>(&sKS[key * 64 + sl * 8]);
            sacc[f] = mfma16(qf[ks], kf, sacc[f]);
        }
    }

    float mx[4] = {-1e30f, -1e30f, -1e30f, -1e30f};
#pragma unroll
    for (int f = 0; f < 14; ++f) {
        const int col = f * 16 + rl;
#pragma unroll
        for (int r = 0; r < 4; ++r) {
            float s = sacc[f][r] * 0.125f;
            if (col >= 217) s = -1e30f;
            sacc[f][r] = s;
            mx[r] = fmaxf(mx[r], s);
        }
    }
#pragma unroll
    for (int o = 1; o < 16; o <<= 1)
#pragma unroll
        for (int r = 0; r < 4; ++r) mx[r] = fmaxf(mx[r], __shfl_xor(mx[r], o));
    float sm[4] = {0.f, 0.f, 0.f, 0.f};
#pragma unroll
    for (int f = 0; f < 14; ++f)
#pragma unroll
        for (int r = 0; r < 4; ++r) {
            float e = __expf(sacc[f][r] - mx[r]);
            sacc[f][r] = e;
            sm[r] += e;
        }
#pragma unroll
    for (int o = 1; o < 16; o <<= 1)
#pragma unroll
        for (int r = 0; r < 4; ++r) sm[r] += __shfl_xor(sm[r], o);
    float inv[4];
#pragma unroll
    for (int r = 0; r < 4; ++r) inv[r] = 1.0f / sm[r];

    __syncthreads();
    unsigned short* Sl = sKS;  // S [4 waves][16 q][232]
#pragma unroll
    for (int f = 0; f < 14; ++f)
#pragma unroll
        for (int r = 0; r < 4; ++r)
            Sl[(wave * 16 + kg * 4 + r) * 232 + f * 16 + rl] = f2bf(sacc[f][r] * inv[r]);
    __syncthreads();

    f32x4 oacc[4];
#pragma unroll
    for (int fd = 0; fd < 4; ++fd) oacc[fd] = f32x4{0.f, 0.f, 0.f, 0.f};
#pragma unroll
    for (int ks = 0; ks < 7; ++ks) {
        sv8 pf = *reinterpret_cast<const sv8*>(&Sl[(wave * 16 + rl) * 232 + ks * 32 + kg * 8]);
#pragma unroll
        for (int fd = 0; fd < 4; ++fd) {
            sv8 vf = *reinterpret_cast<const sv8*>(&sV[(fd * 16 + rl) * 232 + ks * 32 + kg * 8]);
            oacc[fd] = mfma16(pf, vf, oacc[fd]);
        }
    }

#pragma unroll
    for (int fd = 0; fd < 4; ++fd)
#pragma unroll
        for (int r = 0; r < 4; ++r) {
            const int q = qt * 64 + wave * 16 + kg * 4 + r;
            if (q < 197)
                obuf[((size_t)b * 197 + q) * 768 + h * 64 + fd * 16 + rl] = f2bf(oacc[fd][r]);
        }
}

// ---------------- host ----------------

extern "C" void kernel_launch(void* const* d_in, const int* in_sizes, int n_in,
                              void* d_out, int out_size, void* d_ws, size_t ws_size,
                              hipStream_t stream) {
    const float* x      = (const float*)d_in[0];
    const float* prompt = (const float*)d_in[1];
    const float* ln1_w  = (const float*)d_in[2];
    const float* ln1_b  = (const float*)d_in[3];
    const float* qkv_w  = (const float*)d_in[4];
    const float* qkv_b  = (const float*)d_in[5];
    const float* proj_w = (const float*)d_in[6];
    const float* proj_b = (const float*)d_in[7];
    const float* ln2_w  = (const float*)d_in[8];
    const float* ln2_b  = (const float*)d_in[9];
    const float* fc1_w  = (const float*)d_in[10];
    const float* fc1_b  = (const float*)d_in[11];
    const float* fc2_w  = (const float*)d_in[12];
    const float* fc2_b  = (const float*)d_in[13];

    char* ws = (char*)d_ws;
    size_t off = 0;
    auto bump = [&](size_t bytes) {
        char* p = ws + off;
        off += (bytes + 255) & ~(size_t)255;
        return p;
    };
    unsigned short* qkvw  = (unsigned short*)bump(2304UL * 768 * 2);
    unsigned short* projw = (unsigned short*)bump(768UL * 768 * 2);
    unsigned short* fc1w  = (unsigned short*)bump(3072UL * 768 * 2);
    unsigned short* fc2w  = (unsigned short*)bump(768UL * 3072 * 2);
    unsigned short* h2    = (unsigned short*)bump(12608UL * 768 * 2);
    float* xmid           = (float*)bump(12608UL * 768 * 4);
    char* pool = ws + off;
    unsigned short* h1   = (unsigned short*)(pool);
    unsigned short* Qg   = (unsigned short*)(pool + 19365888UL);
    unsigned short* Kg   = (unsigned short*)(pool + 38731776UL);
    unsigned short* Vtg  = (unsigned short*)(pool + 60751872UL);
    unsigned short* obuf = (unsigned short*)(pool + 82771968UL);
    unsigned short* mbuf = (unsigned short*)(pool);  // aliases h1/Q/K/Vt (dead by fc1)

    cvt_bf16_kernel<<<(2304 * 768 / 4 + 255) / 256, 256, 0, stream>>>(qkv_w, qkvw, 2304 * 768 / 4);
    cvt_bf16_kernel<<<(768 * 768 / 4 + 255) / 256, 256, 0, stream>>>(proj_w, projw, 768 * 768 / 4);
    cvt_bf16_kernel<<<(3072 * 768 / 4 + 255) / 256, 256, 0, stream>>>(fc1_w, fc1w, 3072 * 768 / 4);
    cvt_bf16_kernel<<<(768 * 3072 / 4 + 255) / 256, 256, 0, stream>>>(fc2_w, fc2w, 768 * 3072 / 4);

    ln_kernel<<<12608, 256, 0, stream>>>(x, ln1_w, ln1_b, h1);
    prompt_kernel<<<983040 / 256, 256, 0, stream>>>(prompt, Kg, Vtg);

    // qkv: 99 m-blocks x 18 n-blocks
    gemm_bf16<EPI_QKV><<<99 * 18, 256, 0, stream>>>(
        h1, qkvw, qkv_b, nullptr, nullptr, Qg, Kg, Vtg, 12608, 2304, 768, 18);

    attn_kernel<<<dim3(4, 12, 64), 256, 0, stream>>>(Qg, Kg, Vtg, obuf);

    // proj: 99 x 6
    gemm_bf16<EPI_RES><<<99 * 6, 256, 0, stream>>>(
        obuf, projw, proj_b, x, xmid, nullptr, nullptr, nullptr, 12608, 768, 768, 6);

    ln_kernel<<<12608, 256, 0, stream>>>(xmid, ln2_w, ln2_b, h2);

    // fc1: 99 x 24
    gemm_bf16<EPI_GELU><<<99 * 24, 256, 0, stream>>>(
        h2, fc1w, fc1_b, nullptr, mbuf, nullptr, nullptr, nullptr, 12608, 3072, 768, 24);

    // fc2: 99 x 6, K=3072
    gemm_bf16<EPI_RES><<<99 * 6, 256, 0, stream>>>(
        mbuf, fc2w, fc2_b, xmid, (float*)d_out, nullptr, nullptr, nullptr, 12608, 768, 3072, 6);
}